// Round 1
// baseline (500.127 us; speedup 1.0000x reference)
//
#include <hip/hip_runtime.h>
#include <hip/hip_bf16.h>

#define ALPHA 0.2f
#define EPS 1e-3f

typedef __bf16 bf16x8 __attribute__((ext_vector_type(8)));
typedef float f32x4 __attribute__((ext_vector_type(4)));

// problem dims
constexpr int B_  = 16;
constexpr int H_  = 128, W_ = 128;
constexpr int C_  = 64;          // input channels
constexpr int C1_ = 256;         // conv1 output channels
constexpr int F_  = 64;          // final channels
constexpr int HP  = 130, WP = 130;    // padded x
constexpr int H2  = 256, W2 = 256;    // upsampled
constexpr int H2P = 258, W2P = 258;   // padded t1

// ws layout (bytes)
constexpr size_t OFF_XPAD = 0;                                   // bf16 [16][130][130][64] = 34,611,200 B
constexpr size_t OFF_T1   = 34611200;                            // bf16 [16][258][258][64] = 136,323,072 B
constexpr size_t OFF_PW1  = OFF_T1 + 136323072;                  // bf16 packed 576*256
constexpr size_t OFF_PW2  = OFF_PW1 + 294912;                    // bf16 packed 640*64
constexpr size_t OFF_SC   = OFF_PW2 + 81920;                     // f32: A1[256],B1[256],A2[64],B2[64]

// ---------------- prep kernels ----------------

__global__ void prep_scales(const float* b1, const float* g1, const float* be1,
                            const float* m1, const float* v1,
                            const float* b2, const float* g2, const float* be2,
                            const float* m2, const float* v2,
                            float* sc) {
    int t = threadIdx.x;
    if (t < 256) {
        float s = g1[t] * rsqrtf(v1[t] + EPS);
        sc[t]       = s;
        sc[256 + t] = (b1[t] - m1[t]) * s + be1[t];
    }
    if (t < 64) {
        float s = g2[t] * rsqrtf(v2[t] + EPS);
        sc[512 + t] = s;
        sc[576 + t] = (b2[t] - m2[t]) * s + be2[t];
    }
}

// Pack weights in MFMA B-fragment order: tile = 16 n x 32 k, element (l*8+j)
// holds W[k = kt*32 + (l>>4)*8 + j][n = nt*16 + (l&15)].
// PW1: kt 0..17, nt 0..15 (288 tiles). PW2: kt 0..19 (last 2 = Wu), nt 0..3 (80 tiles).
__global__ void pack_w(const float* W1f, const float* W2f, const float* Wuf,
                       __hip_bfloat16* pw1, __hip_bfloat16* pw2) {
    int blk = blockIdx.x;
    int l = threadIdx.x;
    if (blk < 288) {
        int kt = blk / 16, nt = blk % 16;
        #pragma unroll
        for (int j = 0; j < 8; ++j) {
            int k = kt * 32 + (l >> 4) * 8 + j;
            int n = nt * 16 + (l & 15);
            pw1[blk * 512 + l * 8 + j] = __float2bfloat16(W1f[k * 256 + n]);
        }
    } else {
        int bi = blk - 288;
        int kt = bi / 4, nt = bi % 4;
        #pragma unroll
        for (int j = 0; j < 8; ++j) {
            int k = kt * 32 + (l >> 4) * 8 + j;
            int n = nt * 16 + (l & 15);
            float v = (k < 576) ? W2f[k * 64 + n] : Wuf[(k - 576) * 64 + n];
            pw2[bi * 512 + l * 8 + j] = __float2bfloat16(v);
        }
    }
}

__global__ void pad_x(const float* x, __hip_bfloat16* xp, int total) {
    for (int e = blockIdx.x * blockDim.x + threadIdx.x; e < total;
         e += gridDim.x * blockDim.x) {
        int c = e & 63;
        int t = e >> 6;
        int xx = t % WP; t /= WP;
        int yy = t % HP; t /= HP;
        int n = t;
        float v = 0.f;
        if (yy >= 1 && yy <= H_ && xx >= 1 && xx <= W_)
            v = x[((n * H_ + (yy - 1)) * W_ + (xx - 1)) * 64 + c];
        xp[e] = __float2bfloat16(v);
    }
}

__global__ void zero_t1_border(__hip_bfloat16* t1) {
    int e = blockIdx.x * blockDim.x + threadIdx.x;
    if (e >= 16 * 1028 * 64) return;
    int c = e & 63;
    int t = e >> 6;
    int p = t % 1028;
    int n = t / 1028;
    int yy, xx;
    if (p < 258)      { yy = 0;   xx = p; }
    else if (p < 516) { yy = 257; xx = p - 258; }
    else { int p2 = p - 516; yy = 1 + (p2 >> 1); xx = (p2 & 1) ? 257 : 0; }
    t1[((n * H2P + yy) * W2P + xx) * 64 + c] = __float2bfloat16(0.f);
}

// ---------------- GEMM1: conv1 + BN + leaky + subpixel ----------------
// M = 16*128*128 spatial, N = 256, K = 576. Block = 4 waves, BM=64, BN=256.
// Wave w owns channels [w*64, w*64+64).
__global__ __launch_bounds__(256, 2)
void gemm1(const __hip_bfloat16* xp, const __hip_bfloat16* pw1,
           const float* sc, __hip_bfloat16* t1) {
    int b = blockIdx.x;                 // 4096
    int n = b >> 8;                     // 256 blocks per image
    int y = (b >> 1) & 127;
    int x0 = (b & 1) * 64;
    int w = threadIdx.x >> 6;
    int l = threadIdx.x & 63;
    int lr = l & 15;                    // A row / B,CD col within tile
    int lk = l >> 4;                    // k group

    f32x4 acc[4][4] = {};

    for (int kt = 0; kt < 18; ++kt) {
        int ky = kt / 6;
        int kx = (kt % 6) >> 1;
        int ci0 = (kt & 1) * 32 + lk * 8;
        bf16x8 a[4], bb[4];
        const __hip_bfloat16* arow =
            xp + ((size_t)(n * HP + (y + ky)) * WP + (x0 + kx)) * 64 + ci0;
        #pragma unroll
        for (int mi = 0; mi < 4; ++mi)
            a[mi] = *(const bf16x8*)(arow + (mi * 16 + lr) * 64);
        const __hip_bfloat16* bp = pw1 + (size_t)(kt * 16 + w * 4) * 512 + l * 8;
        #pragma unroll
        for (int ni = 0; ni < 4; ++ni)
            bb[ni] = *(const bf16x8*)(bp + ni * 512);
        #pragma unroll
        for (int mi = 0; mi < 4; ++mi)
            #pragma unroll
            for (int ni = 0; ni < 4; ++ni)
                acc[mi][ni] = __builtin_amdgcn_mfma_f32_16x16x32_bf16(
                    a[mi], bb[ni], acc[mi][ni], 0, 0, 0);
    }

    // epilogue: scale/shift + leaky + subpixel scatter into padded t1 (bf16)
    #pragma unroll
    for (int ni = 0; ni < 4; ++ni) {
        int c = w * 64 + ni * 16 + lr;
        float s  = sc[c];
        float sh = sc[256 + c];
        int g  = c >> 2;
        int hi = (c >> 1) & 1;
        int wi = c & 1;
        #pragma unroll
        for (int mi = 0; mi < 4; ++mi) {
            #pragma unroll
            for (int r = 0; r < 4; ++r) {
                int xsp = x0 + mi * 16 + lk * 4 + r;   // row = (l>>4)*4 + reg
                float v = acc[mi][ni][r] * s + sh;
                v = (v >= 0.f) ? v : ALPHA * v;
                int Y = 2 * y + wi, X = 2 * xsp + hi;
                t1[((size_t)(n * H2P + (Y + 1)) * W2P + (X + 1)) * 64 + g] =
                    __float2bfloat16(v);
            }
        }
    }
}

// ---------------- GEMM2: conv2 + BN + leaky + residual(1x1 on upsampled x) ----------------
// M = 16*256*256, N = 64. Block = one output row (256 px), wave w owns X in [w*64, w*64+64).
__global__ __launch_bounds__(256, 2)
void gemm2(const __hip_bfloat16* t1, const __hip_bfloat16* xp,
           const __hip_bfloat16* pw2, const float* sc, const float* bu,
           float* out) {
    int b = blockIdx.x;                 // 4096
    int n = b >> 8;
    int Y = b & 255;
    int w = threadIdx.x >> 6;
    int l = threadIdx.x & 63;
    int lr = l & 15;
    int lk = l >> 4;
    int X0 = w * 64;

    f32x4 am[4][4] = {};
    f32x4 ai[4][4] = {};

    // main conv2 over t1 (K = 576)
    for (int kt = 0; kt < 18; ++kt) {
        int ky = kt / 6;
        int kx = (kt % 6) >> 1;
        int ci0 = (kt & 1) * 32 + lk * 8;
        bf16x8 a[4], bb[4];
        const __hip_bfloat16* arow =
            t1 + ((size_t)(n * H2P + (Y + ky)) * W2P + (X0 + kx)) * 64 + ci0;
        #pragma unroll
        for (int mi = 0; mi < 4; ++mi)
            a[mi] = *(const bf16x8*)(arow + (mi * 16 + lr) * 64);
        const __hip_bfloat16* bp = pw2 + (size_t)(kt * 4) * 512 + l * 8;
        #pragma unroll
        for (int ni = 0; ni < 4; ++ni)
            bb[ni] = *(const bf16x8*)(bp + ni * 512);
        #pragma unroll
        for (int mi = 0; mi < 4; ++mi)
            #pragma unroll
            for (int ni = 0; ni < 4; ++ni)
                am[mi][ni] = __builtin_amdgcn_mfma_f32_16x16x32_bf16(
                    a[mi], bb[ni], am[mi][ni], 0, 0, 0);
    }

    // residual: 1x1 conv on nearest-upsampled x (K = 64), separate accumulator
    #pragma unroll
    for (int kt2 = 0; kt2 < 2; ++kt2) {
        int ci0 = kt2 * 32 + lk * 8;
        bf16x8 a[4], bb[4];
        #pragma unroll
        for (int mi = 0; mi < 4; ++mi) {
            int X = X0 + mi * 16 + lr;
            a[mi] = *(const bf16x8*)(
                xp + ((size_t)(n * HP + (Y >> 1) + 1) * WP + (X >> 1) + 1) * 64 + ci0);
        }
        const __hip_bfloat16* bp = pw2 + (size_t)((18 + kt2) * 4) * 512 + l * 8;
        #pragma unroll
        for (int ni = 0; ni < 4; ++ni)
            bb[ni] = *(const bf16x8*)(bp + ni * 512);
        #pragma unroll
        for (int mi = 0; mi < 4; ++mi)
            #pragma unroll
            for (int ni = 0; ni < 4; ++ni)
                ai[mi][ni] = __builtin_amdgcn_mfma_f32_16x16x32_bf16(
                    a[mi], bb[ni], ai[mi][ni], 0, 0, 0);
    }

    // epilogue
    #pragma unroll
    for (int ni = 0; ni < 4; ++ni) {
        int c = ni * 16 + lr;
        float s  = sc[512 + c];
        float sh = sc[576 + c];
        float bc = bu[c];
        #pragma unroll
        for (int mi = 0; mi < 4; ++mi) {
            #pragma unroll
            for (int r = 0; r < 4; ++r) {
                int X = X0 + mi * 16 + lk * 4 + r;
                float v = am[mi][ni][r] * s + sh;
                v = (v >= 0.f) ? v : ALPHA * v;
                v = v + ai[mi][ni][r] + bc;
                v = (v >= 0.f) ? v : ALPHA * v;
                out[((size_t)(n * H2 + Y) * W2 + X) * 64 + c] = v;
            }
        }
    }
}

// ---------------- launcher ----------------

extern "C" void kernel_launch(void* const* d_in, const int* in_sizes, int n_in,
                              void* d_out, int out_size, void* d_ws, size_t ws_size,
                              hipStream_t stream) {
    const float* x   = (const float*)d_in[0];
    const float* W1  = (const float*)d_in[1];
    const float* b1  = (const float*)d_in[2];
    const float* g1  = (const float*)d_in[3];
    const float* be1 = (const float*)d_in[4];
    const float* m1  = (const float*)d_in[5];
    const float* v1  = (const float*)d_in[6];
    const float* W2  = (const float*)d_in[7];
    const float* b2  = (const float*)d_in[8];
    const float* g2  = (const float*)d_in[9];
    const float* be2 = (const float*)d_in[10];
    const float* m2  = (const float*)d_in[11];
    const float* v2  = (const float*)d_in[12];
    const float* Wu  = (const float*)d_in[13];
    const float* bu  = (const float*)d_in[14];
    float* out = (float*)d_out;

    char* ws = (char*)d_ws;
    __hip_bfloat16* xp  = (__hip_bfloat16*)(ws + OFF_XPAD);
    __hip_bfloat16* t1  = (__hip_bfloat16*)(ws + OFF_T1);
    __hip_bfloat16* pw1 = (__hip_bfloat16*)(ws + OFF_PW1);
    __hip_bfloat16* pw2 = (__hip_bfloat16*)(ws + OFF_PW2);
    float* sc = (float*)(ws + OFF_SC);

    prep_scales<<<1, 256, 0, stream>>>(b1, g1, be1, m1, v1, b2, g2, be2, m2, v2, sc);
    pack_w<<<368, 64, 0, stream>>>(W1, W2, Wu, pw1, pw2);
    pad_x<<<2048, 256, 0, stream>>>(x, xp, B_ * HP * WP * 64);
    zero_t1_border<<<(16 * 1028 * 64 + 255) / 256, 256, 0, stream>>>(t1);
    gemm1<<<4096, 256, 0, stream>>>(xp, pw1, sc, t1);
    gemm2<<<4096, 256, 0, stream>>>(t1, xp, pw2, sc, bu, out);
}